// Round 8
// baseline (177.366 us; speedup 1.0000x reference)
//
#include <hip/hip_runtime.h>
#include <math.h>

#define NTOK 1024
#define QDIM 512
#define NH 8
#define DHD 64

using s16x8 = __attribute__((ext_vector_type(8))) short;
using f32x4 = __attribute__((ext_vector_type(4))) float;

__device__ __forceinline__ unsigned short f2bf(float x) {
  union { float f; unsigned u; } v; v.f = x;
  unsigned r = (v.u + 0x7fffu + ((v.u >> 16) & 1u)) >> 16;
  return (unsigned short)r;
}
__device__ __forceinline__ float bf2f(unsigned short h) {
  union { unsigned u; float f; } v; v.u = ((unsigned)h) << 16;
  return v.f;
}
__device__ __forceinline__ unsigned cvt_pk_bf16(float lo, float hi) {
  unsigned r;
  asm volatile("v_cvt_pk_bf16_f32 %0, %1, %2" : "=v"(r) : "v"(lo), "v"(hi));
  return r;
}

// ---------------- cast x + weights to bf16 ----------------
__global__ __launch_bounds__(256) void cast_kernel(
    const float* __restrict__ x, const float* __restrict__ Wq, const float* __restrict__ Wk,
    const float* __restrict__ Wv, const float* __restrict__ Wo, unsigned short* __restrict__ dst)
{
  const int tid = blockIdx.x * 256 + threadIdx.x;
  const int e = tid * 4;
  const float* src;
  if (e < 1048576) {
    src = x + e;
  } else {
    const int we = e - 1048576;
    const int wi = we >> 18;
    const int off = we & 262143;
    src = (wi == 0 ? Wq : wi == 1 ? Wk : wi == 2 ? Wv : Wo) + off;
  }
  float4 v = *(const float4*)src;
  ushort4 o;
  o.x = f2bf(v.x); o.y = f2bf(v.y); o.z = f2bf(v.z); o.w = f2bf(v.w);
  *(ushort4*)&dst[e] = o;
}

// ---------------- QKV projection (MFMA, kt-prefetch): q pre-scaled ----------------
__global__ __launch_bounds__(256) void proj_mfma_kernel(
    const unsigned short* __restrict__ x_b, const unsigned short* __restrict__ w_b,
    unsigned short* __restrict__ q_b, unsigned short* __restrict__ k_b,
    unsigned short* __restrict__ v_b)
{
  const int w = threadIdx.x >> 6;
  const int l = threadIdx.x & 63;
  const int lq = l & 15, lg = l >> 4;
  const int tile = blockIdx.x * 4 + w;
  const int mat = blockIdx.y >> 3;
  const int h = blockIdx.y & 7;
  const unsigned short* W = w_b + (size_t)mat * 262144 + (size_t)(h * 64) * QDIM;
  const int tok0 = tile * 16;

  const unsigned short* xp = &x_b[(size_t)(tok0 + lq) * QDIM + lg * 8];
  const unsigned short* wp = &W[(size_t)lq * QDIM + lg * 8];

  f32x4 acc[4] = {};
  s16x8 aA, bA[4], aB, bB[4];
  aA = *(const s16x8*)&xp[0];
#pragma unroll
  for (int nf = 0; nf < 4; ++nf) bA[nf] = *(const s16x8*)&wp[(size_t)nf * 16 * QDIM];

  for (int kt = 0; kt < 16; kt += 2) {
    aB = *(const s16x8*)&xp[(kt + 1) * 32];
#pragma unroll
    for (int nf = 0; nf < 4; ++nf) bB[nf] = *(const s16x8*)&wp[(size_t)nf * 16 * QDIM + (kt + 1) * 32];
#pragma unroll
    for (int nf = 0; nf < 4; ++nf)
      acc[nf] = __builtin_amdgcn_mfma_f32_16x16x32_bf16(aA, bA[nf], acc[nf], 0, 0, 0);
    if (kt + 2 < 16) {
      aA = *(const s16x8*)&xp[(kt + 2) * 32];
#pragma unroll
      for (int nf = 0; nf < 4; ++nf) bA[nf] = *(const s16x8*)&wp[(size_t)nf * 16 * QDIM + (kt + 2) * 32];
    }
#pragma unroll
    for (int nf = 0; nf < 4; ++nf)
      acc[nf] = __builtin_amdgcn_mfma_f32_16x16x32_bf16(aB, bB[nf], acc[nf], 0, 0, 0);
  }

  const float scale = (mat == 0) ? 0.125f : 1.0f;
  unsigned short* dst = (mat == 0 ? q_b : mat == 1 ? k_b : v_b);
  const int b = tok0 >> 10;
  const int tl0 = tok0 & 1023;
  unsigned short* dp = dst + (size_t)(b * NH + h) * NTOK * DHD;
#pragma unroll
  for (int nf = 0; nf < 4; ++nf)
#pragma unroll
    for (int r = 0; r < 4; ++r)
      dp[(size_t)(tl0 + lg * 4 + r) * DHD + nf * 16 + lq] = f2bf(acc[nf][r] * scale);
}

// ---------------- AdaIN stats: per-chunk partials, no atomics ----------------
__global__ __launch_bounds__(256) void adain_stats_kernel(
    const unsigned short* __restrict__ k_b, const unsigned short* __restrict__ v_b,
    const float* __restrict__ mask, float* __restrict__ stats_p, float* __restrict__ stats_cnt)
{
  const int id = blockIdx.x;              // 256 = arr(2) x h(8) x ch(16)
  const int arr = id >> 7, h = (id >> 4) & 7, ch = id & 15;
  const unsigned short* base = arr ? v_b : k_b;
  const unsigned short* refp = base + (size_t)h * 65536;
  const unsigned short* fep  = base + (size_t)(8 + h) * 65536;
  const int t = threadIdx.x, dh = t & 63, ig = t >> 6;

  if (arr == 0 && h == 0 && t < 64) {
    const int tok = ch * 64 + t;
    float c = mask[(tok >> 5) * 128 + (tok & 31) * 2];
#pragma unroll
    for (int off = 1; off < 64; off <<= 1) c += __shfl_xor(c, off);
    if (t == 0) stats_cnt[ch] = c;
  }

  float rs = 0.f, rq = 0.f, fs = 0.f, fq = 0.f;
  for (int i = 0; i < 16; ++i) {
    const int tok = ch * 64 + ig * 16 + i;
    const float rv = bf2f(refp[(size_t)tok * DHD + dh]);
    rs += rv; rq += rv * rv;
    const float fv = bf2f(fep[(size_t)tok * DHD + dh]);
    const float mm = mask[(tok >> 5) * 128 + (tok & 31) * 2];
    fs += mm * fv; fq += mm * fv * fv;
  }
  __shared__ float red[4][256];
  red[0][t] = rs; red[1][t] = rq; red[2][t] = fs; red[3][t] = fq;
  __syncthreads();
  if (ig == 0) {
    rs = red[0][dh] + red[0][dh + 64] + red[0][dh + 128] + red[0][dh + 192];
    rq = red[1][dh] + red[1][dh + 64] + red[1][dh + 128] + red[1][dh + 192];
    fs = red[2][dh] + red[2][dh + 64] + red[2][dh + 128] + red[2][dh + 192];
    fq = red[3][dh] + red[3][dh + 64] + red[3][dh + 128] + red[3][dh + 192];
    float* sp = stats_p + (size_t)id * 256;
    sp[dh] = rs; sp[64 + dh] = rq; sp[128 + dh] = fs; sp[192 + dh] = fq;
  }
}

// ---------------- AdaIN apply: reduce partials inline, then transform ----------------
__global__ __launch_bounds__(256) void adain_apply_kernel(
    unsigned short* __restrict__ k_b, unsigned short* __restrict__ v_b,
    const float* __restrict__ mask, const float* __restrict__ stats_p,
    const float* __restrict__ stats_cnt)
{
  const int id = blockIdx.x;
  const int arr = id >> 7, h = (id >> 4) & 7, ch = id & 15;
  unsigned short* fep = (arr ? v_b : k_b) + (size_t)(8 + h) * 65536;
  const int t = threadIdx.x, dh = t & 63, ig = t >> 6;

  __shared__ float sA[64], sB[64];
  if (t < 64) {
    float cnt = 0.f;
#pragma unroll
    for (int c = 0; c < 16; ++c) cnt += stats_cnt[c];
    const float* sp = stats_p + (size_t)((arr << 7) | (h << 4)) * 256;
    float rs = 0.f, rq = 0.f, fs = 0.f, fq = 0.f;
#pragma unroll
    for (int c = 0; c < 16; ++c) {
      rs += sp[c * 256 + t]; rq += sp[c * 256 + 64 + t];
      fs += sp[c * 256 + 128 + t]; fq += sp[c * 256 + 192 + t];
    }
    const float rmean = rs * (1.0f / 1024.0f);
    const float rstd = sqrtf(fmaxf((rq - 1024.0f * rmean * rmean) * (1.0f / 1023.0f), 0.f));
    const float fmean = fs / cnt;
    const float fstd = sqrtf(fmaxf((fq - cnt * fmean * fmean) / (cnt - 1.0f), 0.f));
    const float a = rstd / fstd;
    sA[t] = a; sB[t] = rmean - fmean * a;
  }
  __syncthreads();
  const float a = sA[dh], bb = sB[dh];
  for (int i = 0; i < 16; ++i) {
    const int tok = ch * 64 + ig * 16 + i;
    if (mask[(tok >> 5) * 128 + (tok & 31) * 2] != 0.f) {
      const float fv = bf2f(fep[(size_t)tok * DHD + dh]);
      fep[(size_t)tok * DHD + dh] = f2bf(fv * a + bb);
    }
  }
}

// ---------------- V transpose (post-AdaIN): v_b [bh][tok][dh] -> v_bT [bh][dh][tok] ----------------
__global__ __launch_bounds__(256) void vtrans_kernel(const unsigned short* __restrict__ v_b,
                                                     unsigned short* __restrict__ v_bT)
{
  const int bh = blockIdx.y;
  const int tc = blockIdx.x;
  __shared__ unsigned short T[64][72];
  const int t = threadIdx.x;
  {
    const int tok = t >> 2, d0 = (t & 3) * 16;
    const unsigned short* src = v_b + ((size_t)bh * NTOK + tc * 64 + tok) * DHD + d0;
    ushort4 a0 = *(const ushort4*)&src[0];
    ushort4 a1 = *(const ushort4*)&src[4];
    ushort4 a2 = *(const ushort4*)&src[8];
    ushort4 a3 = *(const ushort4*)&src[12];
    T[d0 + 0][tok] = a0.x; T[d0 + 1][tok] = a0.y; T[d0 + 2][tok] = a0.z; T[d0 + 3][tok] = a0.w;
    T[d0 + 4][tok] = a1.x; T[d0 + 5][tok] = a1.y; T[d0 + 6][tok] = a1.z; T[d0 + 7][tok] = a1.w;
    T[d0 + 8][tok] = a2.x; T[d0 + 9][tok] = a2.y; T[d0 +10][tok] = a2.z; T[d0 +11][tok] = a2.w;
    T[d0 +12][tok] = a3.x; T[d0 +13][tok] = a3.y; T[d0 +14][tok] = a3.z; T[d0 +15][tok] = a3.w;
  }
  __syncthreads();
  {
    const int dh = t >> 2, t0 = (t & 3) * 16;
    unsigned short* dst = v_bT + ((size_t)bh * DHD + dh) * NTOK + tc * 64 + t0;
    s16x8 r0 = *(const s16x8*)&T[dh][t0];
    s16x8 r1 = *(const s16x8*)&T[dh][t0 + 8];
    *(s16x8*)&dst[0] = r0;
    *(s16x8*)&dst[8] = r1;
  }
}

// ---------------- attention partial: 1 wave per (bh, qtile, kv-slot)  [R4 verbatim] ----------------
__global__ __launch_bounds__(64) void attn_part_kernel(
    const unsigned short* __restrict__ q_b, const unsigned short* __restrict__ k_b,
    const unsigned short* __restrict__ v_bT, const float* __restrict__ mask,
    unsigned short* __restrict__ pO, float* __restrict__ pml)
{
  const int id = blockIdx.x;              // 4096 = bh(16) x qt(64) x s(4)
  const int bh = id >> 8, b = bh >> 3, h = bh & 7;
  const int qt = (id >> 2) & 63, s = id & 3;
  const int q0 = qt * 16;
  const int l = threadIdx.x, lq = l & 15, lg = l >> 4;

  __shared__ unsigned int P_u[16][36];

  const unsigned short* qrow = q_b + ((size_t)bh * NTOK + q0 + lq) * DHD + lg * 8;
  s16x8 qf0 = *(const s16x8*)&qrow[0];
  s16x8 qf1 = *(const s16x8*)&qrow[32];

  const int qtok = q0 + lq;
  const float mneg = (b == 1) ? (1.0f - mask[(qtok >> 5) * 128 + (qtok & 31) * 2]) * (-1e9f) : 0.0f;

  const size_t own = (size_t)bh * 65536, ref = (size_t)h * 65536;
  const int ntile = (b == 0) ? 4 : 8;     // b0: 4x64=256 kv; b1: 8x64=512 kv
  const int kv0 = s * ((b == 0) ? 256 : 512);

  float mrow = -1e30f, lrow = 0.f;
  f32x4 oacc[4] = {};

  for (int tt = 0; tt < ntile; ++tt) {
    const int kvtok = kv0 + tt * 64;
    const int inref = (kvtok >= NTOK) ? 1 : 0;
    const size_t base = inref ? ref : own;
    const int off = inref ? (kvtok - NTOK) : kvtok;
    const unsigned short* kp = k_b + base + (size_t)off * DHD;
    const unsigned short* vp = v_bT + base + off;

    // S^T = K . Q^T
    f32x4 sf[4];
#pragma unroll
    for (int mf = 0; mf < 4; ++mf) {
      s16x8 a0 = *(const s16x8*)&kp[(size_t)(mf * 16 + lq) * DHD + lg * 8];
      s16x8 a1 = *(const s16x8*)&kp[(size_t)(mf * 16 + lq) * DHD + 32 + lg * 8];
      f32x4 z = {};
      z = __builtin_amdgcn_mfma_f32_16x16x32_bf16(a0, qf0, z, 0, 0, 0);
      sf[mf] = __builtin_amdgcn_mfma_f32_16x16x32_bf16(a1, qf1, z, 0, 0, 0);
    }

    const float add = inref ? mneg : 0.0f;
    float tm = -1e30f;
#pragma unroll
    for (int mf = 0; mf < 4; ++mf)
#pragma unroll
      for (int r = 0; r < 4; ++r) { sf[mf][r] += add; tm = fmaxf(tm, sf[mf][r]); }
    tm = fmaxf(tm, __shfl_xor(tm, 16));
    tm = fmaxf(tm, __shfl_xor(tm, 32));

    if (!__all(tm <= mrow + 8.0f)) {
      const float mnew = fmaxf(mrow, tm);
      const float alpha = __expf(mrow - mnew);
      mrow = mnew;
      lrow *= alpha;
      float ar[4];
#pragma unroll
      for (int r = 0; r < 4; ++r) ar[r] = __shfl(alpha, lg * 4 + r, 16);
#pragma unroll
      for (int nf = 0; nf < 4; ++nf)
#pragma unroll
        for (int r = 0; r < 4; ++r) oacc[nf][r] *= ar[r];
    }

    float p[4][4];
    float ps = 0.f;
#pragma unroll
    for (int mf = 0; mf < 4; ++mf)
#pragma unroll
      for (int r = 0; r < 4; ++r) { const float e = __expf(sf[mf][r] - mrow); p[mf][r] = e; ps += e; }
    ps += __shfl_xor(ps, 16);
    ps += __shfl_xor(ps, 32);
    lrow += ps;

#pragma unroll
    for (int mf = 0; mf < 4; ++mf) {
      uint2 wv;
      wv.x = cvt_pk_bf16(p[mf][0], p[mf][1]);
      wv.y = cvt_pk_bf16(p[mf][2], p[mf][3]);
      *(uint2*)&P_u[lq][8 * mf + 2 * lg] = wv;
    }

    // O += P . V
#pragma unroll
    for (int ks = 0; ks < 2; ++ks) {
      s16x8 pa = *(const s16x8*)&P_u[lq][16 * ks + 4 * lg];
#pragma unroll
      for (int nf = 0; nf < 4; ++nf) {
        s16x8 vb = *(const s16x8*)&vp[(size_t)(nf * 16 + lq) * NTOK + ks * 32 + lg * 8];
        oacc[nf] = __builtin_amdgcn_mfma_f32_16x16x32_bf16(pa, vb, oacc[nf], 0, 0, 0);
      }
    }
  }

  const int u = (bh * 64 + qt) * 4 + s;
  unsigned short* pop = pO + (size_t)u * 1024;
#pragma unroll
  for (int nf = 0; nf < 4; ++nf)
#pragma unroll
    for (int r = 0; r < 4; ++r)
      pop[(size_t)(lg * 4 + r) * DHD + nf * 16 + lq] = f2bf(oacc[nf][r]);
  if (l < 16) {
    pml[(size_t)u * 32 + lq] = mrow;
    pml[(size_t)u * 32 + 16 + lq] = lrow;
  }
}

// ---------------- attention merge: combine 4 partials per (bh, qtile)  [R4 verbatim] ----------------
__global__ __launch_bounds__(64) void attn_merge_kernel(
    const unsigned short* __restrict__ pO, const float* __restrict__ pml,
    unsigned short* __restrict__ o_b)
{
  const int id = blockIdx.x;              // 1024 = bh(16) x qt(64)
  const int bh = id >> 6, qt = id & 63;
  const int l = threadIdx.x, r = l & 15, dblk = l >> 4;
  const int d0 = dblk * 16;
  const int base_u = (bh * 64 + qt) * 4;

  float ms[4], ls[4];
  float M = -1e30f;
#pragma unroll
  for (int s = 0; s < 4; ++s) {
    ms[s] = pml[(size_t)(base_u + s) * 32 + r];
    ls[s] = pml[(size_t)(base_u + s) * 32 + 16 + r];
    M = fmaxf(M, ms[s]);
  }
  float Lsum = 0.f;
  float o[16];
#pragma unroll
  for (int j = 0; j < 16; ++j) o[j] = 0.f;
#pragma unroll
  for (int s = 0; s < 4; ++s) {
    const float alpha = __expf(ms[s] - M);
    Lsum += alpha * ls[s];
    const unsigned short* po = pO + (size_t)(base_u + s) * 1024 + (size_t)r * DHD + d0;
    s16x8 a = *(const s16x8*)&po[0];
    s16x8 c = *(const s16x8*)&po[8];
#pragma unroll
    for (int j = 0; j < 8; ++j) {
      o[j] += alpha * bf2f((unsigned short)a[j]);
      o[8 + j] += alpha * bf2f((unsigned short)c[j]);
    }
  }
  const float inv = 1.0f / Lsum;
  unsigned short* dst = o_b + ((size_t)bh * NTOK + qt * 16 + r) * DHD + d0;
  ushort4 w0, w1, w2, w3;
  w0.x = f2bf(o[0] * inv);  w0.y = f2bf(o[1] * inv);  w0.z = f2bf(o[2] * inv);  w0.w = f2bf(o[3] * inv);
  w1.x = f2bf(o[4] * inv);  w1.y = f2bf(o[5] * inv);  w1.z = f2bf(o[6] * inv);  w1.w = f2bf(o[7] * inv);
  w2.x = f2bf(o[8] * inv);  w2.y = f2bf(o[9] * inv);  w2.z = f2bf(o[10] * inv); w2.w = f2bf(o[11] * inv);
  w3.x = f2bf(o[12] * inv); w3.y = f2bf(o[13] * inv); w3.z = f2bf(o[14] * inv); w3.w = f2bf(o[15] * inv);
  *(ushort4*)&dst[0] = w0; *(ushort4*)&dst[4] = w1;
  *(ushort4*)&dst[8] = w2; *(ushort4*)&dst[12] = w3;
}

// ---------------- output projection (MFMA, kt-prefetch) + bias, fp32 out ----------------
__global__ __launch_bounds__(256) void outproj_mfma_kernel(
    const unsigned short* __restrict__ o_b, const unsigned short* __restrict__ Wo_b,
    const float* __restrict__ bo, float* __restrict__ out)
{
  const int w = threadIdx.x >> 6, l = threadIdx.x & 63;
  const int lq = l & 15, lg = l >> 4;
  const int tile = blockIdx.x * 4 + w;
  const int c0 = blockIdx.y * 64;
  const int tok = tile * 16 + lq;
  const int b = tok >> 10, tl = tok & 1023;

  const unsigned short* obase = o_b + (size_t)(b * NH) * NTOK * DHD + (size_t)tl * DHD + lg * 8;
  const unsigned short* wp = &Wo_b[(size_t)(c0 + lq) * QDIM + lg * 8];

#define OP_A(KT) (*(const s16x8*)&obase[(size_t)((KT) >> 1) * NTOK * DHD + ((KT) & 1) * 32])

  f32x4 acc[4] = {};
  s16x8 aA, bA[4], aB, bB[4];
  aA = OP_A(0);
#pragma unroll
  for (int nf = 0; nf < 4; ++nf) bA[nf] = *(const s16x8*)&wp[(size_t)nf * 16 * QDIM];

  for (int kt = 0; kt < 16; kt += 2) {
    aB = OP_A(kt + 1);
#pragma unroll
    for (int nf = 0; nf < 4; ++nf) bB[nf] = *(const s16x8*)&wp[(size_t)nf * 16 * QDIM + (kt + 1) * 32];
#pragma unroll
    for (int nf = 0; nf < 4; ++nf)
      acc[nf] = __builtin_amdgcn_mfma_f32_16x16x32_bf16(aA, bA[nf], acc[nf], 0, 0, 0);
    if (kt + 2 < 16) {
      aA = OP_A(kt + 2);
#pragma unroll
      for (int nf = 0; nf < 4; ++nf) bA[nf] = *(const s16x8*)&wp[(size_t)nf * 16 * QDIM + (kt + 2) * 32];
    }
#pragma unroll
    for (int nf = 0; nf < 4; ++nf)
      acc[nf] = __builtin_amdgcn_mfma_f32_16x16x32_bf16(aB, bB[nf], acc[nf], 0, 0, 0);
  }
#undef OP_A

  const int row0 = tile * 16;
#pragma unroll
  for (int nf = 0; nf < 4; ++nf) {
    const float bv = bo[c0 + nf * 16 + lq];
#pragma unroll
    for (int r = 0; r < 4; ++r)
      out[(size_t)(row0 + lg * 4 + r) * QDIM + c0 + nf * 16 + lq] = acc[nf][r] + bv;
  }
}

extern "C" void kernel_launch(void* const* d_in, const int* in_sizes, int n_in,
                              void* d_out, int out_size, void* d_ws, size_t ws_size,
                              hipStream_t stream) {
  const float* x    = (const float*)d_in[0];
  const float* mask = (const float*)d_in[1];
  const float* Wq   = (const float*)d_in[2];
  const float* Wk   = (const float*)d_in[3];
  const float* Wv   = (const float*)d_in[4];
  const float* Wo   = (const float*)d_in[5];
  const float* bo   = (const float*)d_in[6];
  float* out = (float*)d_out;

  char* ws = (char*)d_ws;
  unsigned short* x_b  = (unsigned short*)ws;                          // 2 MB
  unsigned short* w_b  = (unsigned short*)(ws + 2097152);              // 2 MB (Wq,Wk,Wv,Wo)
  unsigned short* Wo_b = (unsigned short*)(ws + 2097152 + 3 * 524288);
  unsigned short* q_b  = (unsigned short*)(ws + 4194304);              // 2 MB
  unsigned short* k_b  = (unsigned short*)(ws + 6291456);              // 2 MB
  unsigned short* v_b  = (unsigned short*)(ws + 8388608);              // 2 MB
  unsigned short* v_bT = (unsigned short*)(ws + 10485760);             // 2 MB
  unsigned short* o_b  = (unsigned short*)(ws + 12582912);             // 2 MB
  unsigned short* pO   = (unsigned short*)(ws + 14680064);             // 8 MB (4096 x 1024 bf16)
  float* pml       = (float*)(ws + 23068672);                          // 512 KB
  float* stats_p   = (float*)(ws + 23592960);                          // 256 KB
  float* stats_cnt = (float*)(ws + 23855104);                          // 64 B

  cast_kernel<<<2048, 256, 0, stream>>>(x, Wq, Wk, Wv, Wo, x_b);
  proj_mfma_kernel<<<dim3(32, 24), 256, 0, stream>>>(x_b, w_b, q_b, k_b, v_b);
  adain_stats_kernel<<<256, 256, 0, stream>>>(k_b, v_b, mask, stats_p, stats_cnt);
  adain_apply_kernel<<<256, 256, 0, stream>>>(k_b, v_b, mask, stats_p, stats_cnt);
  vtrans_kernel<<<dim3(16, 16), 256, 0, stream>>>(v_b, v_bT);
  attn_part_kernel<<<4096, 64, 0, stream>>>(q_b, k_b, v_bT, mask, pO, pml);
  attn_merge_kernel<<<1024, 64, 0, stream>>>(pO, pml, o_b);
  outproj_mfma_kernel<<<dim3(32, 8), 256, 0, stream>>>(o_b, Wo_b, bo, out);
}

// Round 9
// 160.996 us; speedup vs baseline: 1.1017x; 1.1017x over previous
//
#include <hip/hip_runtime.h>
#include <math.h>

#define NTOK 1024
#define QDIM 512
#define NH 8
#define DHD 64

using s16x8 = __attribute__((ext_vector_type(8))) short;
using f32x4 = __attribute__((ext_vector_type(4))) float;

__device__ __forceinline__ unsigned short f2bf(float x) {
  union { float f; unsigned u; } v; v.f = x;
  unsigned r = (v.u + 0x7fffu + ((v.u >> 16) & 1u)) >> 16;
  return (unsigned short)r;
}
__device__ __forceinline__ float bf2f(unsigned short h) {
  union { unsigned u; float f; } v; v.u = ((unsigned)h) << 16;
  return v.f;
}
__device__ __forceinline__ unsigned cvt_pk_bf16(float lo, float hi) {
  unsigned r;
  asm volatile("v_cvt_pk_bf16_f32 %0, %1, %2" : "=v"(r) : "v"(lo), "v"(hi));
  return r;
}

// ---------------- cast x + weights to bf16 ----------------
__global__ __launch_bounds__(256) void cast_kernel(
    const float* __restrict__ x, const float* __restrict__ Wq, const float* __restrict__ Wk,
    const float* __restrict__ Wv, const float* __restrict__ Wo, unsigned short* __restrict__ dst)
{
  const int tid = blockIdx.x * 256 + threadIdx.x;
  const int e = tid * 4;
  const float* src;
  if (e < 1048576) {
    src = x + e;
  } else {
    const int we = e - 1048576;
    const int wi = we >> 18;
    const int off = we & 262143;
    src = (wi == 0 ? Wq : wi == 1 ? Wk : wi == 2 ? Wv : Wo) + off;
  }
  float4 v = *(const float4*)src;
  ushort4 o;
  o.x = f2bf(v.x); o.y = f2bf(v.y); o.z = f2bf(v.z); o.w = f2bf(v.w);
  *(ushort4*)&dst[e] = o;
}

// ---------------- QKV projection (MFMA, kt-prefetch): q pre-scaled ----------------
__global__ __launch_bounds__(256) void proj_mfma_kernel(
    const unsigned short* __restrict__ x_b, const unsigned short* __restrict__ w_b,
    unsigned short* __restrict__ q_b, unsigned short* __restrict__ k_b,
    unsigned short* __restrict__ v_b)
{
  const int w = threadIdx.x >> 6;
  const int l = threadIdx.x & 63;
  const int lq = l & 15, lg = l >> 4;
  const int tile = blockIdx.x * 4 + w;
  const int mat = blockIdx.y >> 3;
  const int h = blockIdx.y & 7;
  const unsigned short* W = w_b + (size_t)mat * 262144 + (size_t)(h * 64) * QDIM;
  const int tok0 = tile * 16;

  const unsigned short* xp = &x_b[(size_t)(tok0 + lq) * QDIM + lg * 8];
  const unsigned short* wp = &W[(size_t)lq * QDIM + lg * 8];

  f32x4 acc[4] = {};
  s16x8 aA, bA[4], aB, bB[4];
  aA = *(const s16x8*)&xp[0];
#pragma unroll
  for (int nf = 0; nf < 4; ++nf) bA[nf] = *(const s16x8*)&wp[(size_t)nf * 16 * QDIM];

  for (int kt = 0; kt < 16; kt += 2) {
    aB = *(const s16x8*)&xp[(kt + 1) * 32];
#pragma unroll
    for (int nf = 0; nf < 4; ++nf) bB[nf] = *(const s16x8*)&wp[(size_t)nf * 16 * QDIM + (kt + 1) * 32];
#pragma unroll
    for (int nf = 0; nf < 4; ++nf)
      acc[nf] = __builtin_amdgcn_mfma_f32_16x16x32_bf16(aA, bA[nf], acc[nf], 0, 0, 0);
    if (kt + 2 < 16) {
      aA = *(const s16x8*)&xp[(kt + 2) * 32];
#pragma unroll
      for (int nf = 0; nf < 4; ++nf) bA[nf] = *(const s16x8*)&wp[(size_t)nf * 16 * QDIM + (kt + 2) * 32];
    }
#pragma unroll
    for (int nf = 0; nf < 4; ++nf)
      acc[nf] = __builtin_amdgcn_mfma_f32_16x16x32_bf16(aB, bB[nf], acc[nf], 0, 0, 0);
  }

  const float scale = (mat == 0) ? 0.125f : 1.0f;
  unsigned short* dst = (mat == 0 ? q_b : mat == 1 ? k_b : v_b);
  const int b = tok0 >> 10;
  const int tl0 = tok0 & 1023;
  unsigned short* dp = dst + (size_t)(b * NH + h) * NTOK * DHD;
#pragma unroll
  for (int nf = 0; nf < 4; ++nf)
#pragma unroll
    for (int r = 0; r < 4; ++r)
      dp[(size_t)(tl0 + lg * 4 + r) * DHD + nf * 16 + lq] = f2bf(acc[nf][r] * scale);
}

// ---------------- AdaIN stats: per-chunk partials, no atomics ----------------
__global__ __launch_bounds__(256) void adain_stats_kernel(
    const unsigned short* __restrict__ k_b, const unsigned short* __restrict__ v_b,
    const float* __restrict__ mask, float* __restrict__ stats_p, float* __restrict__ stats_cnt)
{
  const int id = blockIdx.x;              // 256 = arr(2) x h(8) x ch(16)
  const int arr = id >> 7, h = (id >> 4) & 7, ch = id & 15;
  const unsigned short* base = arr ? v_b : k_b;
  const unsigned short* refp = base + (size_t)h * 65536;
  const unsigned short* fep  = base + (size_t)(8 + h) * 65536;
  const int t = threadIdx.x, dh = t & 63, ig = t >> 6;

  if (arr == 0 && h == 0 && t < 64) {
    const int tok = ch * 64 + t;
    float c = mask[(tok >> 5) * 128 + (tok & 31) * 2];
#pragma unroll
    for (int off = 1; off < 64; off <<= 1) c += __shfl_xor(c, off);
    if (t == 0) stats_cnt[ch] = c;
  }

  float rs = 0.f, rq = 0.f, fs = 0.f, fq = 0.f;
  for (int i = 0; i < 16; ++i) {
    const int tok = ch * 64 + ig * 16 + i;
    const float rv = bf2f(refp[(size_t)tok * DHD + dh]);
    rs += rv; rq += rv * rv;
    const float fv = bf2f(fep[(size_t)tok * DHD + dh]);
    const float mm = mask[(tok >> 5) * 128 + (tok & 31) * 2];
    fs += mm * fv; fq += mm * fv * fv;
  }
  __shared__ float red[4][256];
  red[0][t] = rs; red[1][t] = rq; red[2][t] = fs; red[3][t] = fq;
  __syncthreads();
  if (ig == 0) {
    rs = red[0][dh] + red[0][dh + 64] + red[0][dh + 128] + red[0][dh + 192];
    rq = red[1][dh] + red[1][dh + 64] + red[1][dh + 128] + red[1][dh + 192];
    fs = red[2][dh] + red[2][dh + 64] + red[2][dh + 128] + red[2][dh + 192];
    fq = red[3][dh] + red[3][dh + 64] + red[3][dh + 128] + red[3][dh + 192];
    float* sp = stats_p + (size_t)id * 256;
    sp[dh] = rs; sp[64 + dh] = rq; sp[128 + dh] = fs; sp[192 + dh] = fq;
  }
}

// ---------------- AdaIN apply ----------------
__global__ __launch_bounds__(256) void adain_apply_kernel(
    unsigned short* __restrict__ k_b, unsigned short* __restrict__ v_b,
    const float* __restrict__ mask, const float* __restrict__ stats_p,
    const float* __restrict__ stats_cnt)
{
  const int id = blockIdx.x;
  const int arr = id >> 7, h = (id >> 4) & 7, ch = id & 15;
  unsigned short* fep = (arr ? v_b : k_b) + (size_t)(8 + h) * 65536;
  const int t = threadIdx.x, dh = t & 63, ig = t >> 6;

  __shared__ float sA[64], sB[64];
  if (t < 64) {
    float cnt = 0.f;
#pragma unroll
    for (int c = 0; c < 16; ++c) cnt += stats_cnt[c];
    const float* sp = stats_p + (size_t)((arr << 7) | (h << 4)) * 256;
    float rs = 0.f, rq = 0.f, fs = 0.f, fq = 0.f;
#pragma unroll
    for (int c = 0; c < 16; ++c) {
      rs += sp[c * 256 + t]; rq += sp[c * 256 + 64 + t];
      fs += sp[c * 256 + 128 + t]; fq += sp[c * 256 + 192 + t];
    }
    const float rmean = rs * (1.0f / 1024.0f);
    const float rstd = sqrtf(fmaxf((rq - 1024.0f * rmean * rmean) * (1.0f / 1023.0f), 0.f));
    const float fmean = fs / cnt;
    const float fstd = sqrtf(fmaxf((fq - cnt * fmean * fmean) / (cnt - 1.0f), 0.f));
    const float a = rstd / fstd;
    sA[t] = a; sB[t] = rmean - fmean * a;
  }
  __syncthreads();
  const float a = sA[dh], bb = sB[dh];
  for (int i = 0; i < 16; ++i) {
    const int tok = ch * 64 + ig * 16 + i;
    if (mask[(tok >> 5) * 128 + (tok & 31) * 2] != 0.f) {
      const float fv = bf2f(fep[(size_t)tok * DHD + dh]);
      fep[(size_t)tok * DHD + dh] = f2bf(fv * a + bb);
    }
  }
}

// ---------------- V transpose (post-AdaIN): v_b [bh][tok][dh] -> v_bT [bh][dh][tok] ----------------
__global__ __launch_bounds__(256) void vtrans_kernel(const unsigned short* __restrict__ v_b,
                                                     unsigned short* __restrict__ v_bT)
{
  const int bh = blockIdx.y;
  const int tc = blockIdx.x;
  __shared__ unsigned short T[64][72];
  const int t = threadIdx.x;
  {
    const int tok = t >> 2, d0 = (t & 3) * 16;
    const unsigned short* src = v_b + ((size_t)bh * NTOK + tc * 64 + tok) * DHD + d0;
    ushort4 a0 = *(const ushort4*)&src[0];
    ushort4 a1 = *(const ushort4*)&src[4];
    ushort4 a2 = *(const ushort4*)&src[8];
    ushort4 a3 = *(const ushort4*)&src[12];
    T[d0 + 0][tok] = a0.x; T[d0 + 1][tok] = a0.y; T[d0 + 2][tok] = a0.z; T[d0 + 3][tok] = a0.w;
    T[d0 + 4][tok] = a1.x; T[d0 + 5][tok] = a1.y; T[d0 + 6][tok] = a1.z; T[d0 + 7][tok] = a1.w;
    T[d0 + 8][tok] = a2.x; T[d0 + 9][tok] = a2.y; T[d0 +10][tok] = a2.z; T[d0 +11][tok] = a2.w;
    T[d0 +12][tok] = a3.x; T[d0 +13][tok] = a3.y; T[d0 +14][tok] = a3.z; T[d0 +15][tok] = a3.w;
  }
  __syncthreads();
  {
    const int dh = t >> 2, t0 = (t & 3) * 16;
    unsigned short* dst = v_bT + ((size_t)bh * DHD + dh) * NTOK + tc * 64 + t0;
    s16x8 r0 = *(const s16x8*)&T[dh][t0];
    s16x8 r1 = *(const s16x8*)&T[dh][t0 + 8];
    *(s16x8*)&dst[0] = r0;
    *(s16x8*)&dst[8] = r1;
  }
}

// ---------------- attention partial: QBLK=32 per wave, 8 kv-slots, 4 waves/block.
// Inner structure = R4 body duplicated for two q-halves sharing K/V loads. ----------------
__global__ __launch_bounds__(256, 4) void attn_part_kernel(
    const unsigned short* __restrict__ q_b, const unsigned short* __restrict__ k_b,
    const unsigned short* __restrict__ v_bT, const float* __restrict__ mask,
    unsigned short* __restrict__ pO, float* __restrict__ pml)
{
  const int w = threadIdx.x >> 6;
  const int unit = blockIdx.x * 4 + w;    // 0..4095; 0..2047: b=1 (long), rest b=0
  int b, rr;
  if (unit < 2048) { b = 1; rr = unit; } else { b = 0; rr = unit - 2048; }
  const int hh = rr >> 8;                 // 0..7
  const int qb = (rr >> 3) & 31;          // 0..31 (32-token q block)
  const int s  = rr & 7;                  // 0..7
  const int bh = b * 8 + hh;
  const int l = threadIdx.x & 63, lq = l & 15, lg = l >> 4;

  __shared__ unsigned int P_u[4][2][16][36];

  const unsigned short* qbase = q_b + ((size_t)bh * NTOK + qb * 32) * DHD;
  s16x8 qfA0 = *(const s16x8*)&qbase[(size_t)lq * DHD + lg * 8];
  s16x8 qfA1 = *(const s16x8*)&qbase[(size_t)lq * DHD + 32 + lg * 8];
  s16x8 qfB0 = *(const s16x8*)&qbase[(size_t)(16 + lq) * DHD + lg * 8];
  s16x8 qfB1 = *(const s16x8*)&qbase[(size_t)(16 + lq) * DHD + 32 + lg * 8];

  const int ntile = (b == 0) ? 2 : 4;     // slot width: b0 128 kv, b1 256 kv
  const int kv0 = s * ntile * 64;
  const int inref = (b == 1 && kv0 >= NTOK) ? 1 : 0;   // slots never cross own/ref
  const int off0 = inref ? (kv0 - NTOK) : kv0;
  const size_t base = (size_t)(inref ? hh : bh) * 65536;
  const unsigned short* kbase = k_b + base + (size_t)off0 * DHD;
  const unsigned short* vbase = v_bT + base + off0;

  float mnegA = 0.f, mnegB = 0.f;
  if (inref) {
    const int qA = qb * 32 + lq, qB = qA + 16;
    mnegA = (1.0f - mask[(qA >> 5) * 128 + (qA & 31) * 2]) * (-1e9f);
    mnegB = (1.0f - mask[(qB >> 5) * 128 + (qB & 31) * 2]) * (-1e9f);
  }

  float mrowA = -1e30f, lrowA = 0.f;
  float mrowB = -1e30f, lrowB = 0.f;
  f32x4 oA[4] = {}, oB[4] = {};

  for (int tt = 0; tt < ntile; ++tt) {
    const unsigned short* kp = kbase + (size_t)tt * 64 * DHD;
    const unsigned short* vp = vbase + tt * 64;

    // S^T = K . Q^T for both q-halves, sharing the K fragments
    f32x4 sfA[4], sfB[4];
#pragma unroll
    for (int mf = 0; mf < 4; ++mf) {
      s16x8 a0 = *(const s16x8*)&kp[(size_t)(mf * 16 + lq) * DHD + lg * 8];
      s16x8 a1 = *(const s16x8*)&kp[(size_t)(mf * 16 + lq) * DHD + 32 + lg * 8];
      f32x4 z0 = {};
      z0 = __builtin_amdgcn_mfma_f32_16x16x32_bf16(a0, qfA0, z0, 0, 0, 0);
      sfA[mf] = __builtin_amdgcn_mfma_f32_16x16x32_bf16(a1, qfA1, z0, 0, 0, 0);
      f32x4 z1 = {};
      z1 = __builtin_amdgcn_mfma_f32_16x16x32_bf16(a0, qfB0, z1, 0, 0, 0);
      sfB[mf] = __builtin_amdgcn_mfma_f32_16x16x32_bf16(a1, qfB1, z1, 0, 0, 0);
    }

    const float addA = inref ? mnegA : 0.0f;
    const float addB = inref ? mnegB : 0.0f;
    float tmA = -1e30f, tmB = -1e30f;
#pragma unroll
    for (int mf = 0; mf < 4; ++mf)
#pragma unroll
      for (int r = 0; r < 4; ++r) {
        sfA[mf][r] += addA; tmA = fmaxf(tmA, sfA[mf][r]);
        sfB[mf][r] += addB; tmB = fmaxf(tmB, sfB[mf][r]);
      }
    tmA = fmaxf(tmA, __shfl_xor(tmA, 16));
    tmA = fmaxf(tmA, __shfl_xor(tmA, 32));
    tmB = fmaxf(tmB, __shfl_xor(tmB, 16));
    tmB = fmaxf(tmB, __shfl_xor(tmB, 32));

    if (!__all(tmA <= mrowA + 8.0f)) {
      const float mnew = fmaxf(mrowA, tmA);
      const float alpha = __expf(mrowA - mnew);
      mrowA = mnew;
      lrowA *= alpha;
      float ar[4];
#pragma unroll
      for (int r = 0; r < 4; ++r) ar[r] = __shfl(alpha, lg * 4 + r, 16);
#pragma unroll
      for (int nf = 0; nf < 4; ++nf)
#pragma unroll
        for (int r = 0; r < 4; ++r) oA[nf][r] *= ar[r];
    }
    if (!__all(tmB <= mrowB + 8.0f)) {
      const float mnew = fmaxf(mrowB, tmB);
      const float alpha = __expf(mrowB - mnew);
      mrowB = mnew;
      lrowB *= alpha;
      float ar[4];
#pragma unroll
      for (int r = 0; r < 4; ++r) ar[r] = __shfl(alpha, lg * 4 + r, 16);
#pragma unroll
      for (int nf = 0; nf < 4; ++nf)
#pragma unroll
        for (int r = 0; r < 4; ++r) oB[nf][r] *= ar[r];
    }

    float pA[4][4], pB[4][4];
    float psA = 0.f, psB = 0.f;
#pragma unroll
    for (int mf = 0; mf < 4; ++mf)
#pragma unroll
      for (int r = 0; r < 4; ++r) {
        const float eA = __expf(sfA[mf][r] - mrowA); pA[mf][r] = eA; psA += eA;
        const float eB = __expf(sfB[mf][r] - mrowB); pB[mf][r] = eB; psB += eB;
      }
    psA += __shfl_xor(psA, 16);
    psA += __shfl_xor(psA, 32);
    lrowA += psA;
    psB += __shfl_xor(psB, 16);
    psB += __shfl_xor(psB, 32);
    lrowB += psB;

#pragma unroll
    for (int mf = 0; mf < 4; ++mf) {
      uint2 wa;
      wa.x = cvt_pk_bf16(pA[mf][0], pA[mf][1]);
      wa.y = cvt_pk_bf16(pA[mf][2], pA[mf][3]);
      *(uint2*)&P_u[w][0][lq][8 * mf + 2 * lg] = wa;
      uint2 wb;
      wb.x = cvt_pk_bf16(pB[mf][0], pB[mf][1]);
      wb.y = cvt_pk_bf16(pB[mf][2], pB[mf][3]);
      *(uint2*)&P_u[w][1][lq][8 * mf + 2 * lg] = wb;
    }

    // O += P . V  (V fragments shared between the two q-halves)
#pragma unroll
    for (int ks = 0; ks < 2; ++ks) {
      s16x8 paA = *(const s16x8*)&P_u[w][0][lq][16 * ks + 4 * lg];
      s16x8 paB = *(const s16x8*)&P_u[w][1][lq][16 * ks + 4 * lg];
#pragma unroll
      for (int nf = 0; nf < 4; ++nf) {
        s16x8 vb = *(const s16x8*)&vp[(size_t)(nf * 16 + lq) * NTOK + ks * 32 + lg * 8];
        oA[nf] = __builtin_amdgcn_mfma_f32_16x16x32_bf16(paA, vb, oA[nf], 0, 0, 0);
        oB[nf] = __builtin_amdgcn_mfma_f32_16x16x32_bf16(paB, vb, oB[nf], 0, 0, 0);
      }
    }
  }

  // unnormalized partial O (32 rows) + per-row (m, l): pml per unit = [mA16|lA16|mB16|lB16]
  const int u = (bh * 32 + qb) * 8 + s;
  unsigned short* pop = pO + (size_t)u * 2048;
#pragma unroll
  for (int nf = 0; nf < 4; ++nf)
#pragma unroll
    for (int r = 0; r < 4; ++r) {
      pop[(size_t)(lg * 4 + r) * DHD + nf * 16 + lq] = f2bf(oA[nf][r]);
      pop[(size_t)(16 + lg * 4 + r) * DHD + nf * 16 + lq] = f2bf(oB[nf][r]);
    }
  if (l < 16) {
    pml[(size_t)u * 64 + lq] = mrowA;
    pml[(size_t)u * 64 + 16 + lq] = lrowA;
  } else if (l < 32) {
    pml[(size_t)u * 64 + 32 + lq] = mrowB;
    pml[(size_t)u * 64 + 48 + lq] = lrowB;
  }
}

// ---------------- attention merge: exp-weighted combine of 8 slots ----------------
__global__ __launch_bounds__(64) void attn_merge_kernel(
    const unsigned short* __restrict__ pO, const float* __restrict__ pml,
    unsigned short* __restrict__ o_b)
{
  const int id = blockIdx.x;              // 1024 = bh(16) x qt16(64)
  const int bh = id >> 6, qt = id & 63;
  const int qb = qt >> 1, half = qt & 1;
  const int l = threadIdx.x, r = l & 15, dblk = l >> 4;
  const int d0 = dblk * 16;
  const int u0 = (bh * 32 + qb) * 8;
  const int mo = half * 32;
  const int row = half * 16 + r;

  float ms[8], ls[8];
  float M = -1e30f;
#pragma unroll
  for (int s = 0; s < 8; ++s) {
    ms[s] = pml[(size_t)(u0 + s) * 64 + mo + r];
    ls[s] = pml[(size_t)(u0 + s) * 64 + mo + 16 + r];
    M = fmaxf(M, ms[s]);
  }
  float Lsum = 0.f;
  float o[16];
#pragma unroll
  for (int j = 0; j < 16; ++j) o[j] = 0.f;
#pragma unroll
  for (int s = 0; s < 8; ++s) {
    const float alpha = __expf(ms[s] - M);
    Lsum += alpha * ls[s];
    const unsigned short* po = pO + (size_t)(u0 + s) * 2048 + (size_t)row * DHD + d0;
    s16x8 a = *(const s16x8*)&po[0];
    s16x8 c = *(const s16x8*)&po[8];
#pragma unroll
    for (int j = 0; j < 8; ++j) {
      o[j] += alpha * bf2f((unsigned short)a[j]);
      o[8 + j] += alpha * bf2f((unsigned short)c[j]);
    }
  }
  const float inv = 1.0f / Lsum;
  unsigned short* dst = o_b + ((size_t)bh * NTOK + qt * 16 + r) * DHD + d0;
  ushort4 w0, w1, w2, w3;
  w0.x = f2bf(o[0] * inv);  w0.y = f2bf(o[1] * inv);  w0.z = f2bf(o[2] * inv);  w0.w = f2bf(o[3] * inv);
  w1.x = f2bf(o[4] * inv);  w1.y = f2bf(o[5] * inv);  w1.z = f2bf(o[6] * inv);  w1.w = f2bf(o[7] * inv);
  w2.x = f2bf(o[8] * inv);  w2.y = f2bf(o[9] * inv);  w2.z = f2bf(o[10] * inv); w2.w = f2bf(o[11] * inv);
  w3.x = f2bf(o[12] * inv); w3.y = f2bf(o[13] * inv); w3.z = f2bf(o[14] * inv); w3.w = f2bf(o[15] * inv);
  *(ushort4*)&dst[0] = w0; *(ushort4*)&dst[4] = w1;
  *(ushort4*)&dst[8] = w2; *(ushort4*)&dst[12] = w3;
}

// ---------------- output projection (MFMA, kt-prefetch) + bias, fp32 out ----------------
__global__ __launch_bounds__(256) void outproj_mfma_kernel(
    const unsigned short* __restrict__ o_b, const unsigned short* __restrict__ Wo_b,
    const float* __restrict__ bo, float* __restrict__ out)
{
  const int w = threadIdx.x >> 6, l = threadIdx.x & 63;
  const int lq = l & 15, lg = l >> 4;
  const int tile = blockIdx.x * 4 + w;
  const int c0 = blockIdx.y * 64;
  const int tok = tile * 16 + lq;
  const int b = tok >> 10, tl = tok & 1023;

  const unsigned short* obase = o_b + (size_t)(b * NH) * NTOK * DHD + (size_t)tl * DHD + lg * 8;
  const unsigned short* wp = &Wo_b[(size_t)(c0 + lq) * QDIM + lg * 8];

#define OP_A(KT) (*(const s16x8*)&obase[(size_t)((KT) >> 1) * NTOK * DHD + ((KT) & 1) * 32])

  f32x4 acc[4] = {};
  s16x8 aA, bA[4], aB, bB[4];
  aA = OP_A(0);
#pragma unroll
  for (int nf = 0; nf < 4; ++nf) bA[nf] = *(const s16x8*)&wp[(size_t)nf * 16 * QDIM];

  for (int kt = 0; kt < 16; kt += 2) {
    aB = OP_A(kt + 1);
#pragma unroll
    for (int nf = 0; nf < 4; ++nf) bB[nf] = *(const s16x8*)&wp[(size_t)nf * 16 * QDIM + (kt + 1) * 32];
#pragma unroll
    for (int nf = 0; nf < 4; ++nf)
      acc[nf] = __builtin_amdgcn_mfma_f32_16x16x32_bf16(aA, bA[nf], acc[nf], 0, 0, 0);
    if (kt + 2 < 16) {
      aA = OP_A(kt + 2);
#pragma unroll
      for (int nf = 0; nf < 4; ++nf) bA[nf] = *(const s16x8*)&wp[(size_t)nf * 16 * QDIM + (kt + 2) * 32];
    }
#pragma unroll
    for (int nf = 0; nf < 4; ++nf)
      acc[nf] = __builtin_amdgcn_mfma_f32_16x16x32_bf16(aB, bB[nf], acc[nf], 0, 0, 0);
  }
#undef OP_A

  const int row0 = tile * 16;
#pragma unroll
  for (int nf = 0; nf < 4; ++nf) {
    const float bv = bo[c0 + nf * 16 + lq];
#pragma unroll
    for (int r = 0; r < 4; ++r)
      out[(size_t)(row0 + lg * 4 + r) * QDIM + c0 + nf * 16 + lq] = acc[nf][r] + bv;
  }
}

extern "C" void kernel_launch(void* const* d_in, const int* in_sizes, int n_in,
                              void* d_out, int out_size, void* d_ws, size_t ws_size,
                              hipStream_t stream) {
  const float* x    = (const float*)d_in[0];
  const float* mask = (const float*)d_in[1];
  const float* Wq   = (const float*)d_in[2];
  const float* Wk   = (const float*)d_in[3];
  const float* Wv   = (const float*)d_in[4];
  const float* Wo   = (const float*)d_in[5];
  const float* bo   = (const float*)d_in[6];
  float* out = (float*)d_out;

  char* ws = (char*)d_ws;
  unsigned short* x_b  = (unsigned short*)ws;                          // 2 MB (dead after proj)
  unsigned short* w_b  = (unsigned short*)(ws + 2097152);              // 2 MB (Wq,Wk,Wv dead after proj)
  unsigned short* Wo_b = (unsigned short*)(ws + 2097152 + 3 * 524288);
  unsigned short* q_b  = (unsigned short*)(ws + 4194304);              // 2 MB
  unsigned short* k_b  = (unsigned short*)(ws + 6291456);              // 2 MB
  unsigned short* v_b  = (unsigned short*)(ws + 8388608);              // 2 MB
  unsigned short* v_bT = (unsigned short*)(ws + 10485760);             // 2 MB
  unsigned short* o_b  = (unsigned short*)(ws + 12582912);             // 2 MB
  unsigned short* pO   = (unsigned short*)(ws + 14680064);             // 16 MB (4096 x 2048 bf16)
  float* pml       = (float*)(ws + 2097152);                           // 1 MB, overlays dead Wq/Wk
  float* stats_p   = (float*)(ws + 0);                                 // 256 KB, overlays dead x_b
  float* stats_cnt = (float*)(ws + 262144);                            // 64 B

  cast_kernel<<<2048, 256, 0, stream>>>(x, Wq, Wk, Wv, Wo, x_b);
  proj_mfma_kernel<<<dim3(32, 24), 256, 0, stream>>>(x_b, w_b, q_b, k_b, v_b);
  adain_stats_kernel<<<256, 256, 0, stream>>>(k_b, v_b, mask, stats_p, stats_cnt);
  adain_apply_kernel<<<256, 256, 0, stream>>>(k_b, v_b, mask, stats_p, stats_cnt);
  vtrans_kernel<<<dim3(16, 16), 256, 0, stream>>>(v_b, v_bT);
  attn_part_kernel<<<1024, 256, 0, stream>>>(q_b, k_b, v_bT, mask, pO, pml);
  attn_merge_kernel<<<1024, 64, 0, stream>>>(pO, pml, o_b);
  outproj_mfma_kernel<<<dim3(32, 8), 256, 0, stream>>>(o_b, Wo_b, bo, out);
}

// Round 10
// 159.951 us; speedup vs baseline: 1.1089x; 1.0065x over previous
//
#include <hip/hip_runtime.h>
#include <math.h>

#define NTOK 1024
#define QDIM 512
#define NH 8
#define DHD 64

using s16x8 = __attribute__((ext_vector_type(8))) short;
using f32x4 = __attribute__((ext_vector_type(4))) float;

__device__ __forceinline__ unsigned short f2bf(float x) {
  union { float f; unsigned u; } v; v.f = x;
  unsigned r = (v.u + 0x7fffu + ((v.u >> 16) & 1u)) >> 16;
  return (unsigned short)r;
}
__device__ __forceinline__ float bf2f(unsigned short h) {
  union { unsigned u; float f; } v; v.u = ((unsigned)h) << 16;
  return v.f;
}
__device__ __forceinline__ unsigned cvt_pk_bf16(float lo, float hi) {
  unsigned r;
  asm volatile("v_cvt_pk_bf16_f32 %0, %1, %2" : "=v"(r) : "v"(lo), "v"(hi));
  return r;
}

// ---------------- cast x + weights to bf16 ----------------
__global__ __launch_bounds__(256) void cast_kernel(
    const float* __restrict__ x, const float* __restrict__ Wq, const float* __restrict__ Wk,
    const float* __restrict__ Wv, const float* __restrict__ Wo, unsigned short* __restrict__ dst)
{
  const int tid = blockIdx.x * 256 + threadIdx.x;
  const int e = tid * 4;
  const float* src;
  if (e < 1048576) {
    src = x + e;
  } else {
    const int we = e - 1048576;
    const int wi = we >> 18;
    const int off = we & 262143;
    src = (wi == 0 ? Wq : wi == 1 ? Wk : wi == 2 ? Wv : Wo) + off;
  }
  float4 v = *(const float4*)src;
  ushort4 o;
  o.x = f2bf(v.x); o.y = f2bf(v.y); o.z = f2bf(v.z); o.w = f2bf(v.w);
  *(ushort4*)&dst[e] = o;
}

// ---------------- QKV projection (MFMA, kt-prefetch, 32 tok/wave): q pre-scaled ----------------
__global__ __launch_bounds__(256) void proj_mfma_kernel(
    const unsigned short* __restrict__ x_b, const unsigned short* __restrict__ w_b,
    unsigned short* __restrict__ q_b, unsigned short* __restrict__ k_b,
    unsigned short* __restrict__ v_b)
{
  const int w = threadIdx.x >> 6;
  const int l = threadIdx.x & 63;
  const int lq = l & 15, lg = l >> 4;
  const int tile = blockIdx.x * 4 + w;          // 0..63 (32-token tiles)
  const int mat = blockIdx.y >> 3;
  const int h = blockIdx.y & 7;
  const unsigned short* W = w_b + (size_t)mat * 262144 + (size_t)(h * 64) * QDIM;
  const int tok0 = tile * 32;

  const unsigned short* xp0 = &x_b[(size_t)(tok0 + lq) * QDIM + lg * 8];
  const unsigned short* xp1 = &x_b[(size_t)(tok0 + 16 + lq) * QDIM + lg * 8];
  const unsigned short* wp = &W[(size_t)lq * QDIM + lg * 8];

  f32x4 acc0[4] = {}, acc1[4] = {};
  s16x8 aA0, aA1, bA[4], aB0, aB1, bB[4];
  aA0 = *(const s16x8*)&xp0[0];
  aA1 = *(const s16x8*)&xp1[0];
#pragma unroll
  for (int nf = 0; nf < 4; ++nf) bA[nf] = *(const s16x8*)&wp[(size_t)nf * 16 * QDIM];

  for (int kt = 0; kt < 16; kt += 2) {
    aB0 = *(const s16x8*)&xp0[(kt + 1) * 32];
    aB1 = *(const s16x8*)&xp1[(kt + 1) * 32];
#pragma unroll
    for (int nf = 0; nf < 4; ++nf) bB[nf] = *(const s16x8*)&wp[(size_t)nf * 16 * QDIM + (kt + 1) * 32];
#pragma unroll
    for (int nf = 0; nf < 4; ++nf) {
      acc0[nf] = __builtin_amdgcn_mfma_f32_16x16x32_bf16(aA0, bA[nf], acc0[nf], 0, 0, 0);
      acc1[nf] = __builtin_amdgcn_mfma_f32_16x16x32_bf16(aA1, bA[nf], acc1[nf], 0, 0, 0);
    }
    if (kt + 2 < 16) {
      aA0 = *(const s16x8*)&xp0[(kt + 2) * 32];
      aA1 = *(const s16x8*)&xp1[(kt + 2) * 32];
#pragma unroll
      for (int nf = 0; nf < 4; ++nf) bA[nf] = *(const s16x8*)&wp[(size_t)nf * 16 * QDIM + (kt + 2) * 32];
    }
#pragma unroll
    for (int nf = 0; nf < 4; ++nf) {
      acc0[nf] = __builtin_amdgcn_mfma_f32_16x16x32_bf16(aB0, bB[nf], acc0[nf], 0, 0, 0);
      acc1[nf] = __builtin_amdgcn_mfma_f32_16x16x32_bf16(aB1, bB[nf], acc1[nf], 0, 0, 0);
    }
  }

  const float scale = (mat == 0) ? 0.125f : 1.0f;
  unsigned short* dst = (mat == 0 ? q_b : mat == 1 ? k_b : v_b);
  const int b = tok0 >> 10;
  const int tl0 = tok0 & 1023;
  unsigned short* dp = dst + (size_t)(b * NH + h) * NTOK * DHD;
#pragma unroll
  for (int nf = 0; nf < 4; ++nf)
#pragma unroll
    for (int r = 0; r < 4; ++r) {
      dp[(size_t)(tl0 + lg * 4 + r) * DHD + nf * 16 + lq] = f2bf(acc0[nf][r] * scale);
      dp[(size_t)(tl0 + 16 + lg * 4 + r) * DHD + nf * 16 + lq] = f2bf(acc1[nf][r] * scale);
    }
}

// ---------------- AdaIN stats: per-chunk partials, no atomics ----------------
__global__ __launch_bounds__(256) void adain_stats_kernel(
    const unsigned short* __restrict__ k_b, const unsigned short* __restrict__ v_b,
    const float* __restrict__ mask, float* __restrict__ stats_p, float* __restrict__ stats_cnt)
{
  const int id = blockIdx.x;              // 256 = arr(2) x h(8) x ch(16)
  const int arr = id >> 7, h = (id >> 4) & 7, ch = id & 15;
  const unsigned short* base = arr ? v_b : k_b;
  const unsigned short* refp = base + (size_t)h * 65536;
  const unsigned short* fep  = base + (size_t)(8 + h) * 65536;
  const int t = threadIdx.x, dh = t & 63, ig = t >> 6;

  if (arr == 0 && h == 0 && t < 64) {
    const int tok = ch * 64 + t;
    float c = mask[(tok >> 5) * 128 + (tok & 31) * 2];
#pragma unroll
    for (int off = 1; off < 64; off <<= 1) c += __shfl_xor(c, off);
    if (t == 0) stats_cnt[ch] = c;
  }

  float rs = 0.f, rq = 0.f, fs = 0.f, fq = 0.f;
  for (int i = 0; i < 16; ++i) {
    const int tok = ch * 64 + ig * 16 + i;
    const float rv = bf2f(refp[(size_t)tok * DHD + dh]);
    rs += rv; rq += rv * rv;
    const float fv = bf2f(fep[(size_t)tok * DHD + dh]);
    const float mm = mask[(tok >> 5) * 128 + (tok & 31) * 2];
    fs += mm * fv; fq += mm * fv * fv;
  }
  __shared__ float red[4][256];
  red[0][t] = rs; red[1][t] = rq; red[2][t] = fs; red[3][t] = fq;
  __syncthreads();
  if (ig == 0) {
    rs = red[0][dh] + red[0][dh + 64] + red[0][dh + 128] + red[0][dh + 192];
    rq = red[1][dh] + red[1][dh + 64] + red[1][dh + 128] + red[1][dh + 192];
    fs = red[2][dh] + red[2][dh + 64] + red[2][dh + 128] + red[2][dh + 192];
    fq = red[3][dh] + red[3][dh + 64] + red[3][dh + 128] + red[3][dh + 192];
    float* sp = stats_p + (size_t)id * 256;
    sp[dh] = rs; sp[64 + dh] = rq; sp[128 + dh] = fs; sp[192 + dh] = fq;
  }
}

// ---------------- AdaIN apply (K only) ----------------
__global__ __launch_bounds__(256) void adain_apply_kernel(
    unsigned short* __restrict__ k_b, unsigned short* __restrict__ v_b,
    const float* __restrict__ mask, const float* __restrict__ stats_p,
    const float* __restrict__ stats_cnt)
{
  const int id = blockIdx.x;              // 128 = arr(=0) x h(8) x ch(16)
  const int arr = id >> 7, h = (id >> 4) & 7, ch = id & 15;
  unsigned short* fep = (arr ? v_b : k_b) + (size_t)(8 + h) * 65536;
  const int t = threadIdx.x, dh = t & 63, ig = t >> 6;

  __shared__ float sA[64], sB[64];
  if (t < 64) {
    float cnt = 0.f;
#pragma unroll
    for (int c = 0; c < 16; ++c) cnt += stats_cnt[c];
    const float* sp = stats_p + (size_t)((arr << 7) | (h << 4)) * 256;
    float rs = 0.f, rq = 0.f, fs = 0.f, fq = 0.f;
#pragma unroll
    for (int c = 0; c < 16; ++c) {
      rs += sp[c * 256 + t]; rq += sp[c * 256 + 64 + t];
      fs += sp[c * 256 + 128 + t]; fq += sp[c * 256 + 192 + t];
    }
    const float rmean = rs * (1.0f / 1024.0f);
    const float rstd = sqrtf(fmaxf((rq - 1024.0f * rmean * rmean) * (1.0f / 1023.0f), 0.f));
    const float fmean = fs / cnt;
    const float fstd = sqrtf(fmaxf((fq - cnt * fmean * fmean) / (cnt - 1.0f), 0.f));
    const float a = rstd / fstd;
    sA[t] = a; sB[t] = rmean - fmean * a;
  }
  __syncthreads();
  const float a = sA[dh], bb = sB[dh];
  for (int i = 0; i < 16; ++i) {
    const int tok = ch * 64 + ig * 16 + i;
    if (mask[(tok >> 5) * 128 + (tok & 31) * 2] != 0.f) {
      const float fv = bf2f(fep[(size_t)tok * DHD + dh]);
      fep[(size_t)tok * DHD + dh] = f2bf(fv * a + bb);
    }
  }
}

// ---------------- V transpose + fused AdaIN apply: v_b -> v_bT ----------------
__global__ __launch_bounds__(256) void vtrans_adain_kernel(
    const unsigned short* __restrict__ v_b, unsigned short* __restrict__ v_bT,
    const float* __restrict__ mask, const float* __restrict__ stats_p,
    const float* __restrict__ stats_cnt)
{
  const int bh = blockIdx.y;
  const int tc = blockIdx.x;
  __shared__ unsigned short T[64][72];
  __shared__ float sA[64], sB[64];
  const int t = threadIdx.x;
  const bool feat = (bh >= 8);

  if (feat) {
    if (t < 64) {
      float cnt = 0.f;
#pragma unroll
      for (int c = 0; c < 16; ++c) cnt += stats_cnt[c];
      const float* sp = stats_p + (size_t)(128 | ((bh - 8) << 4)) * 256;   // arr=1
      float rs = 0.f, rq = 0.f, fs = 0.f, fq = 0.f;
#pragma unroll
      for (int c = 0; c < 16; ++c) {
        rs += sp[c * 256 + t]; rq += sp[c * 256 + 64 + t];
        fs += sp[c * 256 + 128 + t]; fq += sp[c * 256 + 192 + t];
      }
      const float rmean = rs * (1.0f / 1024.0f);
      const float rstd = sqrtf(fmaxf((rq - 1024.0f * rmean * rmean) * (1.0f / 1023.0f), 0.f));
      const float fmean = fs / cnt;
      const float fstd = sqrtf(fmaxf((fq - cnt * fmean * fmean) / (cnt - 1.0f), 0.f));
      const float a = rstd / fstd;
      sA[t] = a; sB[t] = rmean - fmean * a;
    }
    __syncthreads();
  }

  {
    const int tok = t >> 2, d0 = (t & 3) * 16;
    const int gtok = tc * 64 + tok;
    const unsigned short* src = v_b + ((size_t)bh * NTOK + gtok) * DHD + d0;
    ushort4 a0 = *(const ushort4*)&src[0];
    ushort4 a1 = *(const ushort4*)&src[4];
    ushort4 a2 = *(const ushort4*)&src[8];
    ushort4 a3 = *(const ushort4*)&src[12];
    unsigned short vv[16] = {a0.x, a0.y, a0.z, a0.w, a1.x, a1.y, a1.z, a1.w,
                             a2.x, a2.y, a2.z, a2.w, a3.x, a3.y, a3.z, a3.w};
    if (feat && mask[(gtok >> 5) * 128 + (gtok & 31) * 2] != 0.f) {
#pragma unroll
      for (int j = 0; j < 16; ++j)
        vv[j] = f2bf(bf2f(vv[j]) * sA[d0 + j] + sB[d0 + j]);
    }
#pragma unroll
    for (int j = 0; j < 16; ++j) T[d0 + j][tok] = vv[j];
  }
  __syncthreads();
  {
    const int dh = t >> 2, t0 = (t & 3) * 16;
    unsigned short* dst = v_bT + ((size_t)bh * DHD + dh) * NTOK + tc * 64 + t0;
    s16x8 r0 = *(const s16x8*)&T[dh][t0];
    s16x8 r1 = *(const s16x8*)&T[dh][t0 + 8];
    *(s16x8*)&dst[0] = r0;
    *(s16x8*)&dst[8] = r1;
  }
}

// ---------------- attention partial: QBLK=32 per wave, 8 kv-slots, 4 waves/block [R9 verbatim] ----------------
__global__ __launch_bounds__(256, 4) void attn_part_kernel(
    const unsigned short* __restrict__ q_b, const unsigned short* __restrict__ k_b,
    const unsigned short* __restrict__ v_bT, const float* __restrict__ mask,
    unsigned short* __restrict__ pO, float* __restrict__ pml)
{
  const int w = threadIdx.x >> 6;
  const int unit = blockIdx.x * 4 + w;    // 0..4095; 0..2047: b=1 (long), rest b=0
  int b, rr;
  if (unit < 2048) { b = 1; rr = unit; } else { b = 0; rr = unit - 2048; }
  const int hh = rr >> 8;                 // 0..7
  const int qb = (rr >> 3) & 31;          // 0..31 (32-token q block)
  const int s  = rr & 7;                  // 0..7
  const int bh = b * 8 + hh;
  const int l = threadIdx.x & 63, lq = l & 15, lg = l >> 4;

  __shared__ unsigned int P_u[4][2][16][36];

  const unsigned short* qbase = q_b + ((size_t)bh * NTOK + qb * 32) * DHD;
  s16x8 qfA0 = *(const s16x8*)&qbase[(size_t)lq * DHD + lg * 8];
  s16x8 qfA1 = *(const s16x8*)&qbase[(size_t)lq * DHD + 32 + lg * 8];
  s16x8 qfB0 = *(const s16x8*)&qbase[(size_t)(16 + lq) * DHD + lg * 8];
  s16x8 qfB1 = *(const s16x8*)&qbase[(size_t)(16 + lq) * DHD + 32 + lg * 8];

  const int ntile = (b == 0) ? 2 : 4;     // slot width: b0 128 kv, b1 256 kv
  const int kv0 = s * ntile * 64;
  const int inref = (b == 1 && kv0 >= NTOK) ? 1 : 0;   // slots never cross own/ref
  const int off0 = inref ? (kv0 - NTOK) : kv0;
  const size_t base = (size_t)(inref ? hh : bh) * 65536;
  const unsigned short* kbase = k_b + base + (size_t)off0 * DHD;
  const unsigned short* vbase = v_bT + base + off0;

  float mnegA = 0.f, mnegB = 0.f;
  if (inref) {
    const int qA = qb * 32 + lq, qB = qA + 16;
    mnegA = (1.0f - mask[(qA >> 5) * 128 + (qA & 31) * 2]) * (-1e9f);
    mnegB = (1.0f - mask[(qB >> 5) * 128 + (qB & 31) * 2]) * (-1e9f);
  }

  float mrowA = -1e30f, lrowA = 0.f;
  float mrowB = -1e30f, lrowB = 0.f;
  f32x4 oA[4] = {}, oB[4] = {};

  for (int tt = 0; tt < ntile; ++tt) {
    const unsigned short* kp = kbase + (size_t)tt * 64 * DHD;
    const unsigned short* vp = vbase + tt * 64;

    // S^T = K . Q^T for both q-halves, sharing the K fragments
    f32x4 sfA[4], sfB[4];
#pragma unroll
    for (int mf = 0; mf < 4; ++mf) {
      s16x8 a0 = *(const s16x8*)&kp[(size_t)(mf * 16 + lq) * DHD + lg * 8];
      s16x8 a1 = *(const s16x8*)&kp[(size_t)(mf * 16 + lq) * DHD + 32 + lg * 8];
      f32x4 z0 = {};
      z0 = __builtin_amdgcn_mfma_f32_16x16x32_bf16(a0, qfA0, z0, 0, 0, 0);
      sfA[mf] = __builtin_amdgcn_mfma_f32_16x16x32_bf16(a1, qfA1, z0, 0, 0, 0);
      f32x4 z1 = {};
      z1 = __builtin_amdgcn_mfma_f32_16x16x32_bf16(a0, qfB0, z1, 0, 0, 0);
      sfB[mf] = __builtin_amdgcn_mfma_f32_16x16x32_bf16(a1, qfB1, z1, 0, 0, 0);
    }

    const float addA = inref ? mnegA : 0.0f;
    const float addB = inref ? mnegB : 0.0f;
    float tmA = -1e30f, tmB = -1e30f;
#pragma unroll
    for (int mf = 0; mf < 4; ++mf)
#pragma unroll
      for (int r = 0; r < 4; ++r) {
        sfA[mf][r] += addA; tmA = fmaxf(tmA, sfA[mf][r]);
        sfB[mf][r] += addB; tmB = fmaxf(tmB, sfB[mf][r]);
      }
    tmA = fmaxf(tmA, __shfl_xor(tmA, 16));
    tmA = fmaxf(tmA, __shfl_xor(tmA, 32));
    tmB = fmaxf(tmB, __shfl_xor(tmB, 16));
    tmB = fmaxf(tmB, __shfl_xor(tmB, 32));

    if (!__all(tmA <= mrowA + 8.0f)) {
      const float mnew = fmaxf(mrowA, tmA);
      const float alpha = __expf(mrowA - mnew);
      mrowA = mnew;
      lrowA *= alpha;
      float ar[4];
#pragma unroll
      for (int r = 0; r < 4; ++r) ar[r] = __shfl(alpha, lg * 4 + r, 16);
#pragma unroll
      for (int nf = 0; nf < 4; ++nf)
#pragma unroll
        for (int r = 0; r < 4; ++r) oA[nf][r] *= ar[r];
    }
    if (!__all(tmB <= mrowB + 8.0f)) {
      const float mnew = fmaxf(mrowB, tmB);
      const float alpha = __expf(mrowB - mnew);
      mrowB = mnew;
      lrowB *= alpha;
      float ar[4];
#pragma unroll
      for (int r = 0; r < 4; ++r) ar[r] = __shfl(alpha, lg * 4 + r, 16);
#pragma unroll
      for (int nf = 0; nf < 4; ++nf)
#pragma unroll
        for (int r = 0; r < 4; ++r) oB[nf][r] *= ar[r];
    }

    float pA[4][4], pB[4][4];
    float psA = 0.f, psB = 0.f;
#pragma unroll
    for (int mf = 0; mf < 4; ++mf)
#pragma unroll
      for (int r = 0; r < 4; ++r) {
        const float eA = __expf(sfA[mf][r] - mrowA); pA[mf][r] = eA; psA += eA;
        const float eB = __expf(sfB[mf][r] - mrowB); pB[mf][r] = eB; psB += eB;
      }
    psA += __shfl_xor(psA, 16);
    psA += __shfl_xor(psA, 32);
    lrowA += psA;
    psB += __shfl_xor(psB, 16);
    psB += __shfl_xor(psB, 32);
    lrowB += psB;

#pragma unroll
    for (int mf = 0; mf < 4; ++mf) {
      uint2 wa;
      wa.x = cvt_pk_bf16(pA[mf][0], pA[mf][1]);
      wa.y = cvt_pk_bf16(pA[mf][2], pA[mf][3]);
      *(uint2*)&P_u[w][0][lq][8 * mf + 2 * lg] = wa;
      uint2 wb;
      wb.x = cvt_pk_bf16(pB[mf][0], pB[mf][1]);
      wb.y = cvt_pk_bf16(pB[mf][2], pB[mf][3]);
      *(uint2*)&P_u[w][1][lq][8 * mf + 2 * lg] = wb;
    }

    // O += P . V  (V fragments shared between the two q-halves)
#pragma unroll
    for (int ks = 0; ks < 2; ++ks) {
      s16x8 paA = *(const s16x8*)&P_u[w][0][lq][16 * ks + 4 * lg];
      s16x8 paB = *(const s16x8*)&P_u[w][1][lq][16 * ks + 4 * lg];
#pragma unroll
      for (int nf = 0; nf < 4; ++nf) {
        s16x8 vb = *(const s16x8*)&vp[(size_t)(nf * 16 + lq) * NTOK + ks * 32 + lg * 8];
        oA[nf] = __builtin_amdgcn_mfma_f32_16x16x32_bf16(paA, vb, oA[nf], 0, 0, 0);
        oB[nf] = __builtin_amdgcn_mfma_f32_16x16x32_bf16(paB, vb, oB[nf], 0, 0, 0);
      }
    }
  }

  // unnormalized partial O (32 rows) + per-row (m, l): pml per unit = [mA16|lA16|mB16|lB16]
  const int u = (bh * 32 + qb) * 8 + s;
  unsigned short* pop = pO + (size_t)u * 2048;
#pragma unroll
  for (int nf = 0; nf < 4; ++nf)
#pragma unroll
    for (int r = 0; r < 4; ++r) {
      pop[(size_t)(lg * 4 + r) * DHD + nf * 16 + lq] = f2bf(oA[nf][r]);
      pop[(size_t)(16 + lg * 4 + r) * DHD + nf * 16 + lq] = f2bf(oB[nf][r]);
    }
  if (l < 16) {
    pml[(size_t)u * 64 + lq] = mrowA;
    pml[(size_t)u * 64 + 16 + lq] = lrowA;
  } else if (l < 32) {
    pml[(size_t)u * 64 + 32 + lq] = mrowB;
    pml[(size_t)u * 64 + 48 + lq] = lrowB;
  }
}

// ---------------- attention merge: exp-weighted combine of 8 slots [R9 verbatim] ----------------
__global__ __launch_bounds__(64) void attn_merge_kernel(
    const unsigned short* __restrict__ pO, const float* __restrict__ pml,
    unsigned short* __restrict__ o_b)
{
  const int id = blockIdx.x;              // 1024 = bh(16) x qt16(64)
  const int bh = id >> 6, qt = id & 63;
  const int qb = qt >> 1, half = qt & 1;
  const int l = threadIdx.x, r = l & 15, dblk = l >> 4;
  const int d0 = dblk * 16;
  const int u0 = (bh * 32 + qb) * 8;
  const int mo = half * 32;
  const int row = half * 16 + r;

  float ms[8], ls[8];
  float M = -1e30f;
#pragma unroll
  for (int s = 0; s < 8; ++s) {
    ms[s] = pml[(size_t)(u0 + s) * 64 + mo + r];
    ls[s] = pml[(size_t)(u0 + s) * 64 + mo + 16 + r];
    M = fmaxf(M, ms[s]);
  }
  float Lsum = 0.f;
  float o[16];
#pragma unroll
  for (int j = 0; j < 16; ++j) o[j] = 0.f;
#pragma unroll
  for (int s = 0; s < 8; ++s) {
    const float alpha = __expf(ms[s] - M);
    Lsum += alpha * ls[s];
    const unsigned short* po = pO + (size_t)(u0 + s) * 2048 + (size_t)row * DHD + d0;
    s16x8 a = *(const s16x8*)&po[0];
    s16x8 c = *(const s16x8*)&po[8];
#pragma unroll
    for (int j = 0; j < 8; ++j) {
      o[j] += alpha * bf2f((unsigned short)a[j]);
      o[8 + j] += alpha * bf2f((unsigned short)c[j]);
    }
  }
  const float inv = 1.0f / Lsum;
  unsigned short* dst = o_b + ((size_t)bh * NTOK + qt * 16 + r) * DHD + d0;
  ushort4 w0, w1, w2, w3;
  w0.x = f2bf(o[0] * inv);  w0.y = f2bf(o[1] * inv);  w0.z = f2bf(o[2] * inv);  w0.w = f2bf(o[3] * inv);
  w1.x = f2bf(o[4] * inv);  w1.y = f2bf(o[5] * inv);  w1.z = f2bf(o[6] * inv);  w1.w = f2bf(o[7] * inv);
  w2.x = f2bf(o[8] * inv);  w2.y = f2bf(o[9] * inv);  w2.z = f2bf(o[10] * inv); w2.w = f2bf(o[11] * inv);
  w3.x = f2bf(o[12] * inv); w3.y = f2bf(o[13] * inv); w3.z = f2bf(o[14] * inv); w3.w = f2bf(o[15] * inv);
  *(ushort4*)&dst[0] = w0; *(ushort4*)&dst[4] = w1;
  *(ushort4*)&dst[8] = w2; *(ushort4*)&dst[12] = w3;
}

// ---------------- output projection (MFMA, kt-prefetch, 32 tok/wave) + bias, fp32 out ----------------
__global__ __launch_bounds__(256) void outproj_mfma_kernel(
    const unsigned short* __restrict__ o_b, const unsigned short* __restrict__ Wo_b,
    const float* __restrict__ bo, float* __restrict__ out)
{
  const int w = threadIdx.x >> 6, l = threadIdx.x & 63;
  const int lq = l & 15, lg = l >> 4;
  const int tile = blockIdx.x * 4 + w;          // 0..63 (32-token tiles)
  const int c0 = blockIdx.y * 64;
  const int tok0 = tile * 32;
  const int b = tok0 >> 10, tl0 = tok0 & 1023;

  const unsigned short* obase0 = o_b + (size_t)(b * NH) * NTOK * DHD + (size_t)(tl0 + lq) * DHD + lg * 8;
  const unsigned short* obase1 = o_b + (size_t)(b * NH) * NTOK * DHD + (size_t)(tl0 + 16 + lq) * DHD + lg * 8;
  const unsigned short* wp = &Wo_b[(size_t)(c0 + lq) * QDIM + lg * 8];

#define OP_A0(KT) (*(const s16x8*)&obase0[(size_t)((KT) >> 1) * NTOK * DHD + ((KT) & 1) * 32])
#define OP_A1(KT) (*(const s16x8*)&obase1[(size_t)((KT) >> 1) * NTOK * DHD + ((KT) & 1) * 32])

  f32x4 acc0[4] = {}, acc1[4] = {};
  s16x8 aA0, aA1, bA[4], aB0, aB1, bB[4];
  aA0 = OP_A0(0);
  aA1 = OP_A1(0);
#pragma unroll
  for (int nf = 0; nf < 4; ++nf) bA[nf] = *(const s16x8*)&wp[(size_t)nf * 16 * QDIM];

  for (int kt = 0; kt < 16; kt += 2) {
    aB0 = OP_A0(kt + 1);
    aB1 = OP_A1(kt + 1);
#pragma unroll
    for (int nf = 0; nf < 4; ++nf) bB[nf] = *(const s16x8*)&wp[(size_t)nf * 16 * QDIM + (kt + 1) * 32];
#pragma unroll
    for (int nf = 0; nf < 4; ++nf) {
      acc0[nf] = __builtin_amdgcn_mfma_f32_16x16x32_bf16(aA0, bA[nf], acc0[nf], 0, 0, 0);
      acc1[nf] = __builtin_amdgcn_mfma_f32_16x16x32_bf16(aA1, bA[nf], acc1[nf], 0, 0, 0);
    }
    if (kt + 2 < 16) {
      aA0 = OP_A0(kt + 2);
      aA1 = OP_A1(kt + 2);
#pragma unroll
      for (int nf = 0; nf < 4; ++nf) bA[nf] = *(const s16x8*)&wp[(size_t)nf * 16 * QDIM + (kt + 2) * 32];
    }
#pragma unroll
    for (int nf = 0; nf < 4; ++nf) {
      acc0[nf] = __builtin_amdgcn_mfma_f32_16x16x32_bf16(aB0, bB[nf], acc0[nf], 0, 0, 0);
      acc1[nf] = __builtin_amdgcn_mfma_f32_16x16x32_bf16(aB1, bB[nf], acc1[nf], 0, 0, 0);
    }
  }
#undef OP_A0
#undef OP_A1

  const int row0 = tile * 32;
#pragma unroll
  for (int nf = 0; nf < 4; ++nf) {
    const float bv = bo[c0 + nf * 16 + lq];
#pragma unroll
    for (int r = 0; r < 4; ++r) {
      out[(size_t)(row0 + lg * 4 + r) * QDIM + c0 + nf * 16 + lq] = acc0[nf][r] + bv;
      out[(size_t)(row0 + 16 + lg * 4 + r) * QDIM + c0 + nf * 16 + lq] = acc1[nf][r] + bv;
    }
  }
}

extern "C" void kernel_launch(void* const* d_in, const int* in_sizes, int n_in,
                              void* d_out, int out_size, void* d_ws, size_t ws_size,
                              hipStream_t stream) {
  const float* x    = (const float*)d_in[0];
  const float* mask = (const float*)d_in[1];
  const float* Wq   = (const float*)d_in[2];
  const float* Wk   = (const float*)d_in[3];
  const float* Wv   = (const float*)d_in[4];
  const float* Wo   = (const float*)d_in[5];
  const float* bo   = (const float*)d_in[6];
  float* out = (float*)d_out;

  char* ws = (char*)d_ws;
  unsigned short* x_b  = (unsigned short*)ws;                          // 2 MB (dead after proj)
  unsigned short* w_b  = (unsigned short*)(ws + 2097152);              // 2 MB (Wq,Wk,Wv dead after proj)
  unsigned short* Wo_b = (unsigned short*)(ws + 2097152 + 3 * 524288);
  unsigned short* q_b  = (unsigned short*)(ws + 4194304);              // 2 MB
  unsigned short* k_b  = (unsigned short*)(ws + 6291456);              // 2 MB
  unsigned short* v_b  = (unsigned short*)(ws + 8388608);              // 2 MB
  unsigned short* v_bT = (unsigned short*)(ws + 10485760);             // 2 MB
  unsigned short* o_b  = (unsigned short*)(ws + 12582912);             // 2 MB
  unsigned short* pO   = (unsigned short*)(ws + 14680064);             // 16 MB (4096 x 2048 bf16)
  float* pml       = (float*)(ws + 2097152);                           // 1 MB, overlays dead Wq/Wk
  float* stats_p   = (float*)(ws + 0);                                 // 256 KB, overlays dead x_b
  float* stats_cnt = (float*)(ws + 262144);                            // 64 B

  cast_kernel<<<2048, 256, 0, stream>>>(x, Wq, Wk, Wv, Wo, x_b);
  proj_mfma_kernel<<<dim3(16, 24), 256, 0, stream>>>(x_b, w_b, q_b, k_b, v_b);
  adain_stats_kernel<<<256, 256, 0, stream>>>(k_b, v_b, mask, stats_p, stats_cnt);
  adain_apply_kernel<<<128, 256, 0, stream>>>(k_b, v_b, mask, stats_p, stats_cnt);
  vtrans_adain_kernel<<<dim3(16, 16), 256, 0, stream>>>(v_b, v_bT, mask, stats_p, stats_cnt);
  attn_part_kernel<<<1024, 256, 0, stream>>>(q_b, k_b, v_bT, mask, pO, pml);
  attn_merge_kernel<<<1024, 64, 0, stream>>>(pO, pml, o_b);
  outproj_mfma_kernel<<<dim3(16, 8), 256, 0, stream>>>(o_b, Wo_b, bo, out);
}